// Round 1
// baseline (371.208 us; speedup 1.0000x reference)
//
#include <hip/hip_runtime.h>
#include <stdint.h>

// ---------------------------------------------------------------------------
// TokenAlignerOT: A = cos(X,Y) [4096x4096]; K = exp(10A); 6 unbalanced-Sinkhorn
// iterations (converged == reference's 250: contraction fi^2 ~ 1e-4/iter);
// T = A*(u K v^T) + delta; out = T @ X.  bf16 MFMA GEMMs, f32 accumulate.
// Workspace: needs 112.04 MiB of d_ws; Yn uses first 16 MiB of d_out (dead
// before final GEMM writes it).
// ---------------------------------------------------------------------------

typedef __attribute__((ext_vector_type(8))) __bf16 bf16x8;
typedef __attribute__((ext_vector_type(4))) float f32x4;
typedef __attribute__((ext_vector_type(8))) unsigned short ushort8;
typedef __attribute__((ext_vector_type(4))) unsigned int uint4v;

#define N_TOK 4096
#define D_EMB 2048
#define FI 0.009900990099009901f   /* reg_m/(reg_m+reg) = 0.001/0.101 */
#define LOG2A (-12.0f)             /* log2(1/4096) */
#define SINK_ITERS 6

__device__ __forceinline__ unsigned short f2bf(float f) {
  union { float f; uint32_t u; } c; c.f = f;
  uint32_t r = (c.u + 0x7FFFu + ((c.u >> 16) & 1u)) >> 16;
  return (unsigned short)r;
}
__device__ __forceinline__ float bf2f(unsigned short h) {
  union { uint32_t u; float f; } c; c.u = ((uint32_t)h) << 16;
  return c.f;
}

// --------------------------- row L2-normalize -> bf16 ----------------------
__global__ __launch_bounds__(256) void rownorm_bf16(const float* __restrict__ in,
                                                    unsigned short* __restrict__ out) {
  const int row = blockIdx.x;
  const int t = threadIdx.x;
  const float* r = in + (size_t)row * D_EMB;
  float4 a = *(const float4*)(r + t * 8);
  float4 b = *(const float4*)(r + t * 8 + 4);
  float s = a.x * a.x + a.y * a.y + a.z * a.z + a.w * a.w
          + b.x * b.x + b.y * b.y + b.z * b.z + b.w * b.w;
#pragma unroll
  for (int off = 32; off; off >>= 1) s += __shfl_xor(s, off);
  __shared__ float wsum[4];
  if ((t & 63) == 0) wsum[t >> 6] = s;
  __syncthreads();
  float tot = wsum[0] + wsum[1] + wsum[2] + wsum[3];
  float scale = 1.0f / fmaxf(sqrtf(tot), 1e-8f);
  ushort8 o;
  o[0] = f2bf(a.x * scale); o[1] = f2bf(a.y * scale);
  o[2] = f2bf(a.z * scale); o[3] = f2bf(a.w * scale);
  o[4] = f2bf(b.x * scale); o[5] = f2bf(b.y * scale);
  o[6] = f2bf(b.z * scale); o[7] = f2bf(b.w * scale);
  *(ushort8*)(out + (size_t)row * D_EMB + t * 8) = o;
}

// --------------------------- transposes ------------------------------------
__global__ __launch_bounds__(256) void transpose_f32_to_bf16(
    const float* __restrict__ in, unsigned short* __restrict__ out, int R, int C) {
  __shared__ float tile[32][33];
  const int bi = blockIdx.y * 32, bj = blockIdx.x * 32;
  const int tx = threadIdx.x, ty = threadIdx.y;
#pragma unroll
  for (int dy = 0; dy < 32; dy += 8)
    tile[ty + dy][tx] = in[(size_t)(bi + ty + dy) * C + bj + tx];
  __syncthreads();
#pragma unroll
  for (int dy = 0; dy < 32; dy += 8)
    out[(size_t)(bj + ty + dy) * R + bi + tx] = f2bf(tile[tx][ty + dy]);
}

__global__ __launch_bounds__(256) void transpose_bf16(
    const unsigned short* __restrict__ in, unsigned short* __restrict__ out, int R, int C) {
  __shared__ unsigned short tile[32][33];
  const int bi = blockIdx.y * 32, bj = blockIdx.x * 32;
  const int tx = threadIdx.x, ty = threadIdx.y;
#pragma unroll
  for (int dy = 0; dy < 32; dy += 8)
    tile[ty + dy][tx] = in[(size_t)(bi + ty + dy) * C + bj + tx];
  __syncthreads();
#pragma unroll
  for (int dy = 0; dy < 32; dy += 8)
    out[(size_t)(bj + ty + dy) * R + bi + tx] = tile[tx][ty + dy];
}

// --------------------------- NT GEMM, bf16 MFMA ----------------------------
// C[i][j] = sum_k A[i][k] * B[j][k]; A: [M][Kd], B: [N][Kd] (both row-major bf16)
// EPI==0: write outAbf = bf16(C), outKbf = bf16(exp(10*C)), ld = Nld
// EPI==1: write outC (f32), ld = Nld
#define BM 128
#define BN 128
#define BK 32
#define LDT 40  /* padded LDS row stride (elements): stride 80B kills ds_read conflicts */

template <int EPI>
__global__ __launch_bounds__(256) void gemm_nt(
    const unsigned short* __restrict__ Amat, const unsigned short* __restrict__ Bmat,
    int Kd, int Nld,
    unsigned short* __restrict__ outAbf, unsigned short* __restrict__ outKbf,
    float* __restrict__ outC) {
  __shared__ alignas(16) unsigned short As[BM * LDT];
  __shared__ alignas(16) unsigned short Bs[BN * LDT];
  const int t = threadIdx.x;
  const int l = t & 63;
  const int w = t >> 6;
  const int bM = blockIdx.y * BM;
  const int bN = blockIdx.x * BN;
  const int wm = (w >> 1) * 64;
  const int wn = (w & 1) * 64;

  // staging: thread t owns chunks t and t+256; chunk c = 8 elems at
  // (row=c>>2, col=(c&3)*8) of the [128][32] tile
  const int row0 = t >> 2;
  const int colo = (t & 3) * 8;
  const int row1 = row0 + 64;

  const unsigned short* gA0 = Amat + (size_t)(bM + row0) * Kd + colo;
  const unsigned short* gA1 = Amat + (size_t)(bM + row1) * Kd + colo;
  const unsigned short* gB0 = Bmat + (size_t)(bN + row0) * Kd + colo;
  const unsigned short* gB1 = Bmat + (size_t)(bN + row1) * Kd + colo;

  f32x4 acc[4][4] = {};

  for (int k0 = 0; k0 < Kd; k0 += BK) {
    uint4v a0 = *(const uint4v*)(gA0 + k0);
    uint4v a1 = *(const uint4v*)(gA1 + k0);
    uint4v b0 = *(const uint4v*)(gB0 + k0);
    uint4v b1 = *(const uint4v*)(gB1 + k0);
    __syncthreads();
    *(uint4v*)&As[row0 * LDT + colo] = a0;
    *(uint4v*)&As[row1 * LDT + colo] = a1;
    *(uint4v*)&Bs[row0 * LDT + colo] = b0;
    *(uint4v*)&Bs[row1 * LDT + colo] = b1;
    __syncthreads();
    bf16x8 af[4], bfr[4];
#pragma unroll
    for (int m = 0; m < 4; ++m)
      af[m] = *(const bf16x8*)&As[(wm + m * 16 + (l & 15)) * LDT + (l >> 4) * 8];
#pragma unroll
    for (int n = 0; n < 4; ++n)
      bfr[n] = *(const bf16x8*)&Bs[(wn + n * 16 + (l & 15)) * LDT + (l >> 4) * 8];
#pragma unroll
    for (int m = 0; m < 4; ++m)
#pragma unroll
      for (int n = 0; n < 4; ++n)
        acc[m][n] = __builtin_amdgcn_mfma_f32_16x16x32_bf16(af[m], bfr[n], acc[m][n], 0, 0, 0);
  }

#pragma unroll
  for (int m = 0; m < 4; ++m) {
#pragma unroll
    for (int n = 0; n < 4; ++n) {
#pragma unroll
      for (int r = 0; r < 4; ++r) {
        const int i = bM + wm + m * 16 + (l >> 4) * 4 + r;  // D row = (lane>>4)*4+reg
        const int j = bN + wn + n * 16 + (l & 15);          // D col = lane&15
        const float aval = acc[m][n][r];
        if (EPI == 0) {
          const size_t idx = (size_t)i * Nld + j;
          outAbf[idx] = f2bf(aval);
          outKbf[idx] = f2bf(__expf(10.0f * aval));
        } else {
          outC[(size_t)i * Nld + j] = aval;
        }
      }
    }
  }
}

// --------------------------- sinkhorn pieces -------------------------------
__global__ void fill_ones(float* v) { v[blockIdx.x * 256 + threadIdx.x] = 1.0f; }

// one wave per row: y = dot(Km[row,:], xin); out[row] = (a / y)^fi via exp2/log2
__global__ __launch_bounds__(256) void matvec_pow(
    const unsigned short* __restrict__ Km, const float* __restrict__ xin,
    float* __restrict__ xout) {
  const int gw = (int)((blockIdx.x * 256 + threadIdx.x) >> 6);
  const int l = threadIdx.x & 63;
  const unsigned short* row = Km + (size_t)gw * N_TOK;
  float s = 0.0f;
#pragma unroll
  for (int c = 0; c < N_TOK; c += 512) {
    const int j = c + l * 8;
    ushort8 kv = *(const ushort8*)(row + j);
    float4 x0 = *(const float4*)(xin + j);
    float4 x1 = *(const float4*)(xin + j + 4);
    s += bf2f(kv[0]) * x0.x + bf2f(kv[1]) * x0.y + bf2f(kv[2]) * x0.z + bf2f(kv[3]) * x0.w
       + bf2f(kv[4]) * x1.x + bf2f(kv[5]) * x1.y + bf2f(kv[6]) * x1.z + bf2f(kv[7]) * x1.w;
  }
#pragma unroll
  for (int off = 32; off; off >>= 1) s += __shfl_xor(s, off);
  if (l == 0) xout[gw] = exp2f(FI * (LOG2A - log2f(s)));
}

// --------------------------- T = A*(u K v) + delta -> bf16 -----------------
__global__ __launch_bounds__(256) void build_T(
    const unsigned short* __restrict__ Abf, const unsigned short* __restrict__ Kbf,
    const float* __restrict__ delta, const float* __restrict__ u,
    const float* __restrict__ v, unsigned short* __restrict__ Tbf) {
  const size_t e = ((size_t)blockIdx.x * 256 + threadIdx.x) * 8;
  const int i = (int)(e >> 12);
  const int j = (int)(e & 4095);
  const float ui = u[i];
  ushort8 av = *(const ushort8*)(Abf + e);
  ushort8 kv = *(const ushort8*)(Kbf + e);
  float4 d0 = *(const float4*)(delta + e);
  float4 d1 = *(const float4*)(delta + e + 4);
  float4 v0 = *(const float4*)(v + j);
  float4 v1 = *(const float4*)(v + j + 4);
  ushort8 o;
  o[0] = f2bf(bf2f(av[0]) * (ui * bf2f(kv[0]) * v0.x) + d0.x);
  o[1] = f2bf(bf2f(av[1]) * (ui * bf2f(kv[1]) * v0.y) + d0.y);
  o[2] = f2bf(bf2f(av[2]) * (ui * bf2f(kv[2]) * v0.z) + d0.z);
  o[3] = f2bf(bf2f(av[3]) * (ui * bf2f(kv[3]) * v0.w) + d0.w);
  o[4] = f2bf(bf2f(av[4]) * (ui * bf2f(kv[4]) * v1.x) + d1.x);
  o[5] = f2bf(bf2f(av[5]) * (ui * bf2f(kv[5]) * v1.y) + d1.y);
  o[6] = f2bf(bf2f(av[6]) * (ui * bf2f(kv[6]) * v1.z) + d1.z);
  o[7] = f2bf(bf2f(av[7]) * (ui * bf2f(kv[7]) * v1.w) + d1.w);
  *(ushort8*)(Tbf + e) = o;
}

// ---------------------------------------------------------------------------
extern "C" void kernel_launch(void* const* d_in, const int* in_sizes, int n_in,
                              void* d_out, int out_size, void* d_ws, size_t ws_size,
                              hipStream_t stream) {
  const float* X = (const float*)d_in[0];
  const float* Y = (const float*)d_in[1];
  const float* delta = (const float*)d_in[2];
  float* out = (float*)d_out;
  uint8_t* ws = (uint8_t*)d_ws;

  const size_t SZ_NN_BF = (size_t)N_TOK * N_TOK * 2;  // 32 MiB
  const size_t SZ_ND_BF = (size_t)N_TOK * D_EMB * 2;  // 16 MiB

  unsigned short* A_bf = (unsigned short*)(ws);                     // [0,32M)
  unsigned short* K_bf = (unsigned short*)(ws + SZ_NN_BF);          // [32M,64M)
  unsigned short* KT_bf = (unsigned short*)(ws + 2 * SZ_NN_BF);     // [64M,96M)
  unsigned short* T_bf = KT_bf;                                     // KT dead before build_T
  unsigned short* Xn = (unsigned short*)(ws + 3 * SZ_NN_BF);        // [96M,112M)
  unsigned short* XT = Xn;                                          // Xn dead after GEMM1
  float* u = (float*)(ws + 3 * SZ_NN_BF + SZ_ND_BF);                // [112M, +16K)
  float* v = u + N_TOK;
  unsigned short* Yn = (unsigned short*)d_out;  // scratch in out buf; dead before GEMM2

  // 1) normalize rows -> bf16
  rownorm_bf16<<<N_TOK, 256, 0, stream>>>(X, Xn);
  rownorm_bf16<<<N_TOK, 256, 0, stream>>>(Y, Yn);
  // 2) A = Xn @ Yn^T (fused: A_bf and K_bf = exp(10A))
  gemm_nt<0><<<dim3(N_TOK / BN, N_TOK / BM), 256, 0, stream>>>(
      Xn, Yn, D_EMB, N_TOK, A_bf, K_bf, nullptr);
  // 3) XT = bf16(X^T)  (overwrites Xn slot), KT = K^T
  transpose_f32_to_bf16<<<dim3(D_EMB / 32, N_TOK / 32), dim3(32, 8), 0, stream>>>(
      X, XT, N_TOK, D_EMB);
  transpose_bf16<<<dim3(N_TOK / 32, N_TOK / 32), dim3(32, 8), 0, stream>>>(
      K_bf, KT_bf, N_TOK, N_TOK);
  // 4) sinkhorn: v=1; iterate u=(a/(Kv))^fi, v=(b/(K^T u))^fi
  fill_ones<<<N_TOK / 256, 256, 0, stream>>>(v);
  for (int it = 0; it < SINK_ITERS; ++it) {
    matvec_pow<<<N_TOK / 4, 256, 0, stream>>>(K_bf, v, u);
    matvec_pow<<<N_TOK / 4, 256, 0, stream>>>(KT_bf, u, v);
  }
  // 5) T = A * (u K v) + delta  (into KT slot)
  build_T<<<(N_TOK / 8) * (N_TOK / 256), 256, 0, stream>>>(A_bf, K_bf, delta, u, v, T_bf);
  // 6) out = T @ X  == NT(T, X^T)
  gemm_nt<1><<<dim3(D_EMB / BN, N_TOK / BM), 256, 0, stream>>>(
      T_bf, XT, N_TOK, D_EMB, nullptr, nullptr, out);
}

// Round 2
// 311.870 us; speedup vs baseline: 1.1903x; 1.1903x over previous
//
#include <hip/hip_runtime.h>
#include <stdint.h>

// ---------------------------------------------------------------------------
// TokenAlignerOT: A = cos(X,Y) [4096x4096]; K = exp(10A); 3 unbalanced-Sinkhorn
// iterations (fi^2 ~ 1e-4 contraction/iter => converged same as ref's 250);
// T = (log K)/10 * (u K v^T) + delta; out = T @ X.  bf16 MFMA GEMMs (m97
// structure: global_load_lds width=16, linear LDS), f32 accumulate.
// Workspace: 80 MiB + 32 KiB of d_ws; Yn parks in d_out (dead before GEMM2).
// ---------------------------------------------------------------------------

typedef __attribute__((ext_vector_type(8))) __bf16 bf16x8;
typedef __attribute__((ext_vector_type(4))) float f32x4;
typedef __attribute__((ext_vector_type(8))) unsigned short ushort8;

#define N_TOK 4096
#define D_EMB 2048
#define FI 0.009900990099009901f   /* reg_m/(reg_m+reg) = 0.001/0.101 */
#define LOG2A (-12.0f)             /* log2(1/4096) */
#define SINK_ITERS 3

__device__ __forceinline__ unsigned short f2bf(float f) {
  union { float f; uint32_t u; } c; c.f = f;
  uint32_t r = (c.u + 0x7FFFu + ((c.u >> 16) & 1u)) >> 16;
  return (unsigned short)r;
}
__device__ __forceinline__ float bf2f(unsigned short h) {
  union { uint32_t u; float f; } c; c.u = ((uint32_t)h) << 16;
  return c.f;
}

// async global->LDS, 16 B per lane; LDS dest must be wave-uniform base
typedef const __attribute__((address_space(1))) unsigned int* as1_u32p;
typedef __attribute__((address_space(3))) unsigned int* as3_u32p;
__device__ __forceinline__ void gload16(const void* g, void* l) {
  __builtin_amdgcn_global_load_lds((as1_u32p)g, (as3_u32p)l, 16, 0, 0);
}

// --------------------------- row L2-normalize -> bf16 ----------------------
__global__ __launch_bounds__(256) void rownorm_bf16(const float* __restrict__ in,
                                                    unsigned short* __restrict__ out) {
  const int row = blockIdx.x;
  const int t = threadIdx.x;
  const float* r = in + (size_t)row * D_EMB;
  float4 a = *(const float4*)(r + t * 8);
  float4 b = *(const float4*)(r + t * 8 + 4);
  float s = a.x * a.x + a.y * a.y + a.z * a.z + a.w * a.w
          + b.x * b.x + b.y * b.y + b.z * b.z + b.w * b.w;
#pragma unroll
  for (int off = 32; off; off >>= 1) s += __shfl_xor(s, off);
  __shared__ float wsum[4];
  if ((t & 63) == 0) wsum[t >> 6] = s;
  __syncthreads();
  float tot = wsum[0] + wsum[1] + wsum[2] + wsum[3];
  float scale = 1.0f / fmaxf(sqrtf(tot), 1e-8f);
  ushort8 o;
  o[0] = f2bf(a.x * scale); o[1] = f2bf(a.y * scale);
  o[2] = f2bf(a.z * scale); o[3] = f2bf(a.w * scale);
  o[4] = f2bf(b.x * scale); o[5] = f2bf(b.y * scale);
  o[6] = f2bf(b.z * scale); o[7] = f2bf(b.w * scale);
  *(ushort8*)(out + (size_t)row * D_EMB + t * 8) = o;
}

// --------------------------- transposes ------------------------------------
__global__ __launch_bounds__(256) void transpose_f32_to_bf16(
    const float* __restrict__ in, unsigned short* __restrict__ out, int R, int C) {
  __shared__ float tile[32][33];
  const int bi = blockIdx.y * 32, bj = blockIdx.x * 32;
  const int tx = threadIdx.x, ty = threadIdx.y;
#pragma unroll
  for (int dy = 0; dy < 32; dy += 8)
    tile[ty + dy][tx] = in[(size_t)(bi + ty + dy) * C + bj + tx];
  __syncthreads();
#pragma unroll
  for (int dy = 0; dy < 32; dy += 8)
    out[(size_t)(bj + ty + dy) * R + bi + tx] = f2bf(tile[tx][ty + dy]);
}

__global__ __launch_bounds__(256) void transpose_bf16(
    const unsigned short* __restrict__ in, unsigned short* __restrict__ out, int R, int C) {
  __shared__ unsigned short tile[32][33];
  const int bi = blockIdx.y * 32, bj = blockIdx.x * 32;
  const int tx = threadIdx.x, ty = threadIdx.y;
#pragma unroll
  for (int dy = 0; dy < 32; dy += 8)
    tile[ty + dy][tx] = in[(size_t)(bi + ty + dy) * C + bj + tx];
  __syncthreads();
#pragma unroll
  for (int dy = 0; dy < 32; dy += 8)
    out[(size_t)(bj + ty + dy) * R + bi + tx] = tile[tx][ty + dy];
}

// --------------------------- NT GEMM, bf16 MFMA (m97 structure) ------------
// C[i][j] = sum_k A[i][k] * B[j][k]; A: [M][Kd], B: [N][Kd] (row-major bf16)
// EPI==0: write outKbf = bf16(exp(10*C)); EPI==1: write outC (f32). ld = Nld.
#define BM 128
#define BN 128
#define BK 32

template <int EPI>
__global__ __launch_bounds__(256) void gemm_nt(
    const unsigned short* __restrict__ Amat, const unsigned short* __restrict__ Bmat,
    int Kd, int Nld,
    unsigned short* __restrict__ outKbf, float* __restrict__ outC) {
  __shared__ alignas(16) unsigned short As[BM * BK];  // linear [128][32]
  __shared__ alignas(16) unsigned short Bs[BN * BK];
  const int t = threadIdx.x;
  const int l = t & 63;
  const int w = t >> 6;
  const int bM = blockIdx.y * BM;
  const int bN = blockIdx.x * BN;
  const int wm = (w >> 1) * 64;
  const int wn = (w & 1) * 64;

  // staging: wave w fills rows [w*32, w*32+32) of each tile via 2 calls of
  // 16 rows (1024 B). HW: lane l lands at base + l*16 B = row(base)+l>>2,
  // col bytes (l&3)*16 -> global src row += l>>2, col elems (l&3)*8.
  const int srow = w * 32 + (l >> 2);
  const int scol = (l & 3) * 8;
  const unsigned short* gA0 = Amat + (size_t)(bM + srow) * Kd + scol;
  const unsigned short* gA1 = gA0 + (size_t)16 * Kd;
  const unsigned short* gB0 = Bmat + (size_t)(bN + srow) * Kd + scol;
  const unsigned short* gB1 = gB0 + (size_t)16 * Kd;
  unsigned short* lA0 = &As[(w * 32) * BK];
  unsigned short* lA1 = &As[(w * 32 + 16) * BK];
  unsigned short* lB0 = &Bs[(w * 32) * BK];
  unsigned short* lB1 = &Bs[(w * 32 + 16) * BK];

  f32x4 acc[4][4] = {};

  for (int k0 = 0; k0 < Kd; k0 += BK) {
    __syncthreads();  // all waves done reading previous tile
    gload16(gA0 + k0, lA0);
    gload16(gA1 + k0, lA1);
    gload16(gB0 + k0, lB0);
    gload16(gB1 + k0, lB1);
    __syncthreads();  // drains vmcnt -> tile visible
    bf16x8 af[4], bfr[4];
#pragma unroll
    for (int m = 0; m < 4; ++m)
      af[m] = *(const bf16x8*)&As[(wm + m * 16 + (l & 15)) * BK + (l >> 4) * 8];
#pragma unroll
    for (int n = 0; n < 4; ++n)
      bfr[n] = *(const bf16x8*)&Bs[(wn + n * 16 + (l & 15)) * BK + (l >> 4) * 8];
#pragma unroll
    for (int m = 0; m < 4; ++m)
#pragma unroll
      for (int n = 0; n < 4; ++n)
        acc[m][n] = __builtin_amdgcn_mfma_f32_16x16x32_bf16(af[m], bfr[n], acc[m][n], 0, 0, 0);
  }

#pragma unroll
  for (int m = 0; m < 4; ++m) {
#pragma unroll
    for (int n = 0; n < 4; ++n) {
#pragma unroll
      for (int r = 0; r < 4; ++r) {
        const int i = bM + wm + m * 16 + (l >> 4) * 4 + r;  // D row = (lane>>4)*4+reg
        const int j = bN + wn + n * 16 + (l & 15);          // D col = lane&15
        const float aval = acc[m][n][r];
        if (EPI == 0) {
          outKbf[(size_t)i * Nld + j] = f2bf(__expf(10.0f * aval));
        } else {
          outC[(size_t)i * Nld + j] = aval;
        }
      }
    }
  }
}

// --------------------------- sinkhorn pieces -------------------------------
__global__ void fill_ones(float* v) { v[blockIdx.x * 256 + threadIdx.x] = 1.0f; }

// one wave per row: y = dot(Km[row,:], xin); out[row] = (a / y)^fi via exp2/log2
__global__ __launch_bounds__(256) void matvec_pow(
    const unsigned short* __restrict__ Km, const float* __restrict__ xin,
    float* __restrict__ xout) {
  const int gw = (int)((blockIdx.x * 256 + threadIdx.x) >> 6);
  const int l = threadIdx.x & 63;
  const unsigned short* row = Km + (size_t)gw * N_TOK;
  float s = 0.0f;
#pragma unroll
  for (int c = 0; c < N_TOK; c += 512) {
    const int j = c + l * 8;
    ushort8 kv = *(const ushort8*)(row + j);
    float4 x0 = *(const float4*)(xin + j);
    float4 x1 = *(const float4*)(xin + j + 4);
    s += bf2f(kv[0]) * x0.x + bf2f(kv[1]) * x0.y + bf2f(kv[2]) * x0.z + bf2f(kv[3]) * x0.w
       + bf2f(kv[4]) * x1.x + bf2f(kv[5]) * x1.y + bf2f(kv[6]) * x1.z + bf2f(kv[7]) * x1.w;
  }
#pragma unroll
  for (int off = 32; off; off >>= 1) s += __shfl_xor(s, off);
  if (l == 0) xout[gw] = exp2f(FI * (LOG2A - log2f(s)));
}

// --------------- T = (logK)/10 * (u K v) + delta -> bf16 -------------------
__global__ __launch_bounds__(256) void build_T(
    const unsigned short* __restrict__ Kbf,
    const float* __restrict__ delta, const float* __restrict__ u,
    const float* __restrict__ v, unsigned short* __restrict__ Tbf) {
  const size_t e = ((size_t)blockIdx.x * 256 + threadIdx.x) * 8;
  const int i = (int)(e >> 12);
  const int j = (int)(e & 4095);
  const float ui = u[i];
  ushort8 kv = *(const ushort8*)(Kbf + e);
  float4 d0 = *(const float4*)(delta + e);
  float4 d1 = *(const float4*)(delta + e + 4);
  float4 v0 = *(const float4*)(v + j);
  float4 v1 = *(const float4*)(v + j + 4);
  ushort8 o;
  float k0 = bf2f(kv[0]), k1 = bf2f(kv[1]), k2 = bf2f(kv[2]), k3 = bf2f(kv[3]);
  float k4 = bf2f(kv[4]), k5 = bf2f(kv[5]), k6 = bf2f(kv[6]), k7 = bf2f(kv[7]);
  o[0] = f2bf(0.1f * __logf(k0) * (ui * k0 * v0.x) + d0.x);
  o[1] = f2bf(0.1f * __logf(k1) * (ui * k1 * v0.y) + d0.y);
  o[2] = f2bf(0.1f * __logf(k2) * (ui * k2 * v0.z) + d0.z);
  o[3] = f2bf(0.1f * __logf(k3) * (ui * k3 * v0.w) + d0.w);
  o[4] = f2bf(0.1f * __logf(k4) * (ui * k4 * v1.x) + d1.x);
  o[5] = f2bf(0.1f * __logf(k5) * (ui * k5 * v1.y) + d1.y);
  o[6] = f2bf(0.1f * __logf(k6) * (ui * k6 * v1.z) + d1.z);
  o[7] = f2bf(0.1f * __logf(k7) * (ui * k7 * v1.w) + d1.w);
  *(ushort8*)(Tbf + e) = o;
}

// ---------------------------------------------------------------------------
extern "C" void kernel_launch(void* const* d_in, const int* in_sizes, int n_in,
                              void* d_out, int out_size, void* d_ws, size_t ws_size,
                              hipStream_t stream) {
  const float* X = (const float*)d_in[0];
  const float* Y = (const float*)d_in[1];
  const float* delta = (const float*)d_in[2];
  float* out = (float*)d_out;
  uint8_t* ws = (uint8_t*)d_ws;

  const size_t SZ_NN_BF = (size_t)N_TOK * N_TOK * 2;  // 32 MiB
  const size_t SZ_ND_BF = (size_t)N_TOK * D_EMB * 2;  // 16 MiB

  unsigned short* K_bf = (unsigned short*)(ws);                  // [0,32M)
  unsigned short* KT_bf = (unsigned short*)(ws + SZ_NN_BF);      // [32M,64M)
  unsigned short* T_bf = KT_bf;                                  // KT dead before build_T
  unsigned short* Xn = (unsigned short*)(ws + 2 * SZ_NN_BF);     // [64M,80M)
  unsigned short* XT = Xn;                                       // Xn dead after GEMM1
  float* u = (float*)(ws + 2 * SZ_NN_BF + SZ_ND_BF);             // [80M, +16K)
  float* v = u + N_TOK;
  unsigned short* Yn = (unsigned short*)d_out;  // scratch in out buf; dead before GEMM2

  // 1) normalize rows -> bf16
  rownorm_bf16<<<N_TOK, 256, 0, stream>>>(X, Xn);
  rownorm_bf16<<<N_TOK, 256, 0, stream>>>(Y, Yn);
  // 2) K = exp(10 * Xn @ Yn^T)
  gemm_nt<0><<<dim3(N_TOK / BN, N_TOK / BM), 256, 0, stream>>>(
      Xn, Yn, D_EMB, N_TOK, K_bf, nullptr);
  // 3) XT = bf16(X^T) (overwrites Xn slot), KT = K^T
  transpose_f32_to_bf16<<<dim3(D_EMB / 32, N_TOK / 32), dim3(32, 8), 0, stream>>>(
      X, XT, N_TOK, D_EMB);
  transpose_bf16<<<dim3(N_TOK / 32, N_TOK / 32), dim3(32, 8), 0, stream>>>(
      K_bf, KT_bf, N_TOK, N_TOK);
  // 4) sinkhorn: v=1; iterate u=(a/(Kv))^fi, v=(b/(K^T u))^fi
  fill_ones<<<N_TOK / 256, 256, 0, stream>>>(v);
  for (int it = 0; it < SINK_ITERS; ++it) {
    matvec_pow<<<N_TOK / 4, 256, 0, stream>>>(K_bf, v, u);
    matvec_pow<<<N_TOK / 4, 256, 0, stream>>>(KT_bf, u, v);
  }
  // 5) T = (logK)/10 * (u K v) + delta  (into KT slot)
  build_T<<<(N_TOK / 8) * (N_TOK / 256), 256, 0, stream>>>(K_bf, delta, u, v, T_bf);
  // 6) out = T @ X  == NT(T, X^T)
  gemm_nt<1><<<dim3(D_EMB / BN, N_TOK / BM), 256, 0, stream>>>(
      T_bf, XT, N_TOK, D_EMB, nullptr, out);
}

// Round 3
// 278.378 us; speedup vs baseline: 1.3335x; 1.1203x over previous
//
#include <hip/hip_runtime.h>
#include <stdint.h>

// ---------------------------------------------------------------------------
// TokenAlignerOT: A = cos(X,Y) [4096x4096]; K = exp(10A); 3 unbalanced-Sinkhorn
// iterations; T = (log K)/10 * (u K v^T) + delta; out = T @ X.
// GEMMs: 256x256 8-phase schedule (T2 swizzle + T3/T4 counted vmcnt + T5
// setprio), bf16 MFMA 16x16x32, f32 accum. GEMM2 is split-K=2 with f32
// atomicAdd epilogue (grid 8x16x2 = 256 blocks = 1/CU).
// Workspace: 80 MiB + 32 KiB of d_ws; Yn parks in d_out (dead before zero).
// ---------------------------------------------------------------------------

typedef __attribute__((ext_vector_type(8))) __bf16 bf16x8;
typedef __attribute__((ext_vector_type(4))) float f32x4;
typedef __attribute__((ext_vector_type(8))) unsigned short ushort8;

#define N_TOK 4096
#define D_EMB 2048
#define FI 0.009900990099009901f   /* reg_m/(reg_m+reg) = 0.001/0.101 */
#define LOG2A (-12.0f)             /* log2(1/4096) */
#define SINK_ITERS 3

__device__ __forceinline__ unsigned short f2bf(float f) {
  union { float f; uint32_t u; } c; c.f = f;
  uint32_t r = (c.u + 0x7FFFu + ((c.u >> 16) & 1u)) >> 16;
  return (unsigned short)r;
}
__device__ __forceinline__ float bf2f(unsigned short h) {
  union { uint32_t u; float f; } c; c.u = ((uint32_t)h) << 16;
  return c.f;
}

// async global->LDS, 16 B per lane; LDS dest is wave-uniform base (+lane*16 HW)
typedef const __attribute__((address_space(1))) unsigned int* as1_u32p;
typedef __attribute__((address_space(3))) unsigned int* as3_u32p;
__device__ __forceinline__ void gload16(const void* g, void* l) {
  __builtin_amdgcn_global_load_lds((as1_u32p)g, (as3_u32p)l, 16, 0, 0);
}

// --------------------------- row L2-normalize -> bf16 ----------------------
__global__ __launch_bounds__(256) void rownorm_bf16(const float* __restrict__ in,
                                                    unsigned short* __restrict__ out) {
  const int row = blockIdx.x;
  const int t = threadIdx.x;
  const float* r = in + (size_t)row * D_EMB;
  float4 a = *(const float4*)(r + t * 8);
  float4 b = *(const float4*)(r + t * 8 + 4);
  float s = a.x * a.x + a.y * a.y + a.z * a.z + a.w * a.w
          + b.x * b.x + b.y * b.y + b.z * b.z + b.w * b.w;
#pragma unroll
  for (int off = 32; off; off >>= 1) s += __shfl_xor(s, off);
  __shared__ float wsum[4];
  if ((t & 63) == 0) wsum[t >> 6] = s;
  __syncthreads();
  float tot = wsum[0] + wsum[1] + wsum[2] + wsum[3];
  float scale = 1.0f / fmaxf(sqrtf(tot), 1e-8f);
  ushort8 o;
  o[0] = f2bf(a.x * scale); o[1] = f2bf(a.y * scale);
  o[2] = f2bf(a.z * scale); o[3] = f2bf(a.w * scale);
  o[4] = f2bf(b.x * scale); o[5] = f2bf(b.y * scale);
  o[6] = f2bf(b.z * scale); o[7] = f2bf(b.w * scale);
  *(ushort8*)(out + (size_t)row * D_EMB + t * 8) = o;
}

// --------------------------- transposes ------------------------------------
__global__ __launch_bounds__(256) void transpose_f32_to_bf16(
    const float* __restrict__ in, unsigned short* __restrict__ out, int R, int C) {
  __shared__ float tile[32][33];
  const int bi = blockIdx.y * 32, bj = blockIdx.x * 32;
  const int tx = threadIdx.x, ty = threadIdx.y;
#pragma unroll
  for (int dy = 0; dy < 32; dy += 8)
    tile[ty + dy][tx] = in[(size_t)(bi + ty + dy) * C + bj + tx];
  __syncthreads();
#pragma unroll
  for (int dy = 0; dy < 32; dy += 8)
    out[(size_t)(bj + ty + dy) * R + bi + tx] = f2bf(tile[tx][ty + dy]);
}

__global__ __launch_bounds__(256) void transpose_bf16(
    const unsigned short* __restrict__ in, unsigned short* __restrict__ out, int R, int C) {
  __shared__ unsigned short tile[32][33];
  const int bi = blockIdx.y * 32, bj = blockIdx.x * 32;
  const int tx = threadIdx.x, ty = threadIdx.y;
#pragma unroll
  for (int dy = 0; dy < 32; dy += 8)
    tile[ty + dy][tx] = in[(size_t)(bi + ty + dy) * C + bj + tx];
  __syncthreads();
#pragma unroll
  for (int dy = 0; dy < 32; dy += 8)
    out[(size_t)(bj + ty + dy) * R + bi + tx] = tile[tx][ty + dy];
}

// ----------------- 256x256 8-phase NT GEMM, bf16 MFMA ----------------------
// C[i][j] = sum_k A[i][k]*B[j][k]; A:[M][ldA], B:[N][ldB] row-major bf16.
// 512 thr = 8 waves (2Mx4N), per-wave 128x64. BK=64, 2 K-tiles double-buffered.
// LDS 128KiB: A [0,64K) = 2 bufs x 256x64; B [64K,128K).
// Swizzle (T2): within a row (128B = 8 chunks of 16B), chunk c holds logical
// chunk c ^ (row&7). Staging pre-swizzles the GLOBAL source col; LDS dest is
// linear (global_load_lds requirement); ds_read applies the same involution.
// EPI==0: out = bf16(exp(10*C)) ; EPI==1: unsafeAtomicAdd f32 (split-K).
template <int EPI>
__global__ __launch_bounds__(512, 2) void gemm256(
    const unsigned short* __restrict__ Amat, const unsigned short* __restrict__ Bmat,
    int ldA, int ldB, int nt, int kSlice, int ldC,
    unsigned short* __restrict__ outKbf, float* __restrict__ outC) {
  __shared__ alignas(16) char smem[131072];
  const int t = threadIdx.x;
  const int l = t & 63;
  const int w = t >> 6;

  // bijective XCD swizzle over the (x,y) plane (nwg % 8 == 0 here)
  const int nwg = gridDim.x * gridDim.y;
  const int lin = blockIdx.y * gridDim.x + blockIdx.x;
  const int lin2 = (lin & 7) * (nwg >> 3) + (lin >> 3);
  const int bx = lin2 % gridDim.x;
  const int by = lin2 / gridDim.x;
  const int bM = by * 256;
  const int bN = bx * 256;
  const int wrow = w >> 2;  // 0..1
  const int wcol = w & 3;   // 0..3
  const int kOff = blockIdx.z * kSlice;

  const unsigned short* Ag = Amat + (size_t)bM * ldA + kOff;
  const unsigned short* Bg = Bmat + (size_t)bN * ldB + kOff;

  // staging lane constants: chunk idx within half = i*512 + w*64 + l
  // -> row_in_half = i*64 + w*8 + (l>>3), col8 = (l&7) ^ (l>>3)  (pre-swizzle)
  const int sl_r = w * 8 + (l >> 3);
  const int sl_c = ((l & 7) ^ (l >> 3)) * 8;
  const int s_lds = w * 1024;  // wave-uniform LDS byte offset for i=0

  // ds_read swizzled chunk-within-row (bytes), per kk; row&7 == l&7 for all frags
  const int rsw0 = (((l >> 4) + 0) ^ (l & 7)) * 16;
  const int rsw1 = (((l >> 4) + 4) ^ (l & 7)) * 16;
  const int arow = l & 15;

  // stage one 128-row half-tile: H = 4k + typ; typ 0/1 = B half0/1, 2/3 = A half0/1
  auto stage = [&](int k, int typ) {
    const int isA = typ >> 1;
    const int half = typ & 1;
    const unsigned short* G = isA ? Ag : Bg;
    const int ld = isA ? ldA : ldB;
    char* base = smem + (isA ? 0 : 65536) + (k & 1) * 32768 + half * 16384;
    const int gr = half * 128 + sl_r;
    const size_t gidx = (size_t)gr * ld + k * 64 + sl_c;
    gload16(G + gidx, base + s_lds);
    gload16(G + gidx + (size_t)64 * ld, base + 8192 + s_lds);
  };

  f32x4 acc[8][4] = {};

  // prologue: B0(0) B1(0) A0(0) A1(0) B0(1) B1(1) = 12 loads; wait all but 4
  stage(0, 0); stage(0, 1); stage(0, 2); stage(0, 3);
  stage(1, 0); stage(1, 1);
  asm volatile("s_waitcnt vmcnt(4)" ::: "memory");
  __builtin_amdgcn_s_barrier();

  for (int k = 0; k < nt; ++k) {
    char* Abase = smem + (k & 1) * 32768;
    char* Bbase = smem + 65536 + (k & 1) * 32768;
    bf16x8 bfrag[4][2];
#pragma unroll
    for (int q = 0; q < 4; ++q) {
      // --- ds_reads for this quadrant (issued before barrier)
      if (q == 0) {
#pragma unroll
        for (int ni = 0; ni < 4; ++ni) {
          const int brow = wcol * 64 + ni * 16 + arow;
          bfrag[ni][0] = *(const bf16x8*)(Bbase + brow * 128 + rsw0);
          bfrag[ni][1] = *(const bf16x8*)(Bbase + brow * 128 + rsw1);
        }
      }
      bf16x8 afrag[2][2];
#pragma unroll
      for (int mi = 0; mi < 2; ++mi) {
        const int row = wrow * 128 + (2 * q + mi) * 16 + arow;
        afrag[mi][0] = *(const bf16x8*)(Abase + row * 128 + rsw0);
        afrag[mi][1] = *(const bf16x8*)(Abase + row * 128 + rsw1);
      }
      // --- stage one half-tile ahead (A of k+1 at q0/q1, B of k+2 at q2/q3)
      if (q == 0) { if (k + 1 < nt) stage(k + 1, 2); }
      if (q == 1) { if (k + 1 < nt) stage(k + 1, 3); }
      if (q == 2) { if (k + 2 < nt) stage(k + 2, 0); }
      if (q == 3) { if (k + 2 < nt) stage(k + 2, 1); }

      __builtin_amdgcn_s_barrier();
      asm volatile("s_waitcnt lgkmcnt(0)" ::: "memory");
      __builtin_amdgcn_sched_barrier(0);
      __builtin_amdgcn_s_setprio(1);
#pragma unroll
      for (int mi = 0; mi < 2; ++mi)
#pragma unroll
        for (int ni = 0; ni < 4; ++ni) {
          acc[2 * q + mi][ni] = __builtin_amdgcn_mfma_f32_16x16x32_bf16(
              afrag[mi][0], bfrag[ni][0], acc[2 * q + mi][ni], 0, 0, 0);
          acc[2 * q + mi][ni] = __builtin_amdgcn_mfma_f32_16x16x32_bf16(
              afrag[mi][1], bfrag[ni][1], acc[2 * q + mi][ni], 0, 0, 0);
        }
      __builtin_amdgcn_s_setprio(0);
      // K-tile boundary: ensure ktile k+1 fully in LDS before anyone reads it.
      // vmcnt BEFORE the closing barrier -> race-free (each wave's own loads
      // drained; barrier then covers all waves).
      if (q == 3) {
        if (k == nt - 2) asm volatile("s_waitcnt vmcnt(0)" ::: "memory");
        else if (k < nt - 2) asm volatile("s_waitcnt vmcnt(4)" ::: "memory");
      }
      __builtin_amdgcn_s_barrier();
    }
  }

  // epilogue: D row = (lane>>4)*4 + r, col = lane&15 (verified convention)
#pragma unroll
  for (int m = 0; m < 8; ++m) {
#pragma unroll
    for (int n = 0; n < 4; ++n) {
#pragma unroll
      for (int r = 0; r < 4; ++r) {
        const int i = bM + wrow * 128 + m * 16 + (l >> 4) * 4 + r;
        const int j = bN + wcol * 64 + n * 16 + (l & 15);
        const float aval = acc[m][n][r];
        if (EPI == 0) {
          outKbf[(size_t)i * ldC + j] = f2bf(__expf(10.0f * aval));
        } else {
          unsafeAtomicAdd(&outC[(size_t)i * ldC + j], aval);
        }
      }
    }
  }
}

// --------------------------- sinkhorn pieces -------------------------------
__global__ void fill_ones(float* v) { v[blockIdx.x * 256 + threadIdx.x] = 1.0f; }

__global__ __launch_bounds__(256) void zero_f32(float4* p) {
  p[(size_t)blockIdx.x * 256 + threadIdx.x] = float4{0.f, 0.f, 0.f, 0.f};
}

// one wave per row: y = dot(Km[row,:], xin); out[row] = (a / y)^fi
__global__ __launch_bounds__(256) void matvec_pow(
    const unsigned short* __restrict__ Km, const float* __restrict__ xin,
    float* __restrict__ xout) {
  const int gw = (int)((blockIdx.x * 256 + threadIdx.x) >> 6);
  const int l = threadIdx.x & 63;
  const unsigned short* row = Km + (size_t)gw * N_TOK;
  float s = 0.0f;
#pragma unroll
  for (int c = 0; c < N_TOK; c += 512) {
    const int j = c + l * 8;
    ushort8 kv = *(const ushort8*)(row + j);
    float4 x0 = *(const float4*)(xin + j);
    float4 x1 = *(const float4*)(xin + j + 4);
    s += bf2f(kv[0]) * x0.x + bf2f(kv[1]) * x0.y + bf2f(kv[2]) * x0.z + bf2f(kv[3]) * x0.w
       + bf2f(kv[4]) * x1.x + bf2f(kv[5]) * x1.y + bf2f(kv[6]) * x1.z + bf2f(kv[7]) * x1.w;
  }
#pragma unroll
  for (int off = 32; off; off >>= 1) s += __shfl_xor(s, off);
  if (l == 0) xout[gw] = exp2f(FI * (LOG2A - log2f(s)));
}

// --------------- T = (logK)/10 * (u K v) + delta -> bf16 -------------------
__global__ __launch_bounds__(256) void build_T(
    const unsigned short* __restrict__ Kbf,
    const float* __restrict__ delta, const float* __restrict__ u,
    const float* __restrict__ v, unsigned short* __restrict__ Tbf) {
  const size_t e = ((size_t)blockIdx.x * 256 + threadIdx.x) * 8;
  const int i = (int)(e >> 12);
  const int j = (int)(e & 4095);
  const float ui = u[i];
  ushort8 kv = *(const ushort8*)(Kbf + e);
  float4 d0 = *(const float4*)(delta + e);
  float4 d1 = *(const float4*)(delta + e + 4);
  float4 v0 = *(const float4*)(v + j);
  float4 v1 = *(const float4*)(v + j + 4);
  ushort8 o;
  float k0 = bf2f(kv[0]), k1 = bf2f(kv[1]), k2 = bf2f(kv[2]), k3 = bf2f(kv[3]);
  float k4 = bf2f(kv[4]), k5 = bf2f(kv[5]), k6 = bf2f(kv[6]), k7 = bf2f(kv[7]);
  o[0] = f2bf(0.1f * __logf(k0) * (ui * k0 * v0.x) + d0.x);
  o[1] = f2bf(0.1f * __logf(k1) * (ui * k1 * v0.y) + d0.y);
  o[2] = f2bf(0.1f * __logf(k2) * (ui * k2 * v0.z) + d0.z);
  o[3] = f2bf(0.1f * __logf(k3) * (ui * k3 * v0.w) + d0.w);
  o[4] = f2bf(0.1f * __logf(k4) * (ui * k4 * v1.x) + d1.x);
  o[5] = f2bf(0.1f * __logf(k5) * (ui * k5 * v1.y) + d1.y);
  o[6] = f2bf(0.1f * __logf(k6) * (ui * k6 * v1.z) + d1.z);
  o[7] = f2bf(0.1f * __logf(k7) * (ui * k7 * v1.w) + d1.w);
  *(ushort8*)(Tbf + e) = o;
}

// ---------------------------------------------------------------------------
extern "C" void kernel_launch(void* const* d_in, const int* in_sizes, int n_in,
                              void* d_out, int out_size, void* d_ws, size_t ws_size,
                              hipStream_t stream) {
  const float* X = (const float*)d_in[0];
  const float* Y = (const float*)d_in[1];
  const float* delta = (const float*)d_in[2];
  float* out = (float*)d_out;
  uint8_t* ws = (uint8_t*)d_ws;

  const size_t SZ_NN_BF = (size_t)N_TOK * N_TOK * 2;  // 32 MiB
  const size_t SZ_ND_BF = (size_t)N_TOK * D_EMB * 2;  // 16 MiB

  unsigned short* K_bf = (unsigned short*)(ws);                  // [0,32M)
  unsigned short* KT_bf = (unsigned short*)(ws + SZ_NN_BF);      // [32M,64M)
  unsigned short* T_bf = KT_bf;                                  // KT dead before build_T
  unsigned short* Xn = (unsigned short*)(ws + 2 * SZ_NN_BF);     // [64M,80M)
  unsigned short* XT = Xn;                                       // Xn dead after GEMM1
  float* u = (float*)(ws + 2 * SZ_NN_BF + SZ_ND_BF);             // [80M, +16K)
  float* v = u + N_TOK;
  unsigned short* Yn = (unsigned short*)d_out;  // scratch in out buf; dead before zero

  // 1) normalize rows -> bf16
  rownorm_bf16<<<N_TOK, 256, 0, stream>>>(X, Xn);
  rownorm_bf16<<<N_TOK, 256, 0, stream>>>(Y, Yn);
  // 2) K = exp(10 * Xn @ Yn^T)   [4096x4096, K=2048, nt=32]
  gemm256<0><<<dim3(16, 16, 1), 512, 0, stream>>>(
      Xn, Yn, D_EMB, D_EMB, D_EMB / 64, 0, N_TOK, K_bf, nullptr);
  // 3) out := 0 (for split-K atomics; frees Yn), XT = bf16(X^T), KT = K^T
  zero_f32<<<(N_TOK * D_EMB / 4) / 256, 256, 0, stream>>>((float4*)out);
  transpose_f32_to_bf16<<<dim3(D_EMB / 32, N_TOK / 32), dim3(32, 8), 0, stream>>>(
      X, XT, N_TOK, D_EMB);
  transpose_bf16<<<dim3(N_TOK / 32, N_TOK / 32), dim3(32, 8), 0, stream>>>(
      K_bf, KT_bf, N_TOK, N_TOK);
  // 4) sinkhorn: v=1; iterate u=(a/(Kv))^fi, v=(b/(K^T u))^fi
  fill_ones<<<N_TOK / 256, 256, 0, stream>>>(v);
  for (int it = 0; it < SINK_ITERS; ++it) {
    matvec_pow<<<N_TOK / 4, 256, 0, stream>>>(K_bf, v, u);
    matvec_pow<<<N_TOK / 4, 256, 0, stream>>>(KT_bf, u, v);
  }
  // 5) T = (logK)/10 * (u K v) + delta  (into KT slot)
  build_T<<<(N_TOK / 8) * (N_TOK / 256), 256, 0, stream>>>(K_bf, delta, u, v, T_bf);
  // 6) out += T @ X  == NT(T, X^T), split-K=2 (z = K-slice of 2048)
  gemm256<1><<<dim3(D_EMB / 256, N_TOK / 256, 2), 512, 0, stream>>>(
      T_bf, XT, N_TOK, N_TOK, D_EMB / 64, D_EMB, D_EMB, nullptr, out);
}